// Round 5
// baseline (228.280 us; speedup 1.0000x reference)
//
#include <hip/hip_runtime.h>
#include <hip/hip_bf16.h>
#include <stdint.h>

typedef unsigned short u16;
typedef unsigned int   u32;
typedef __bf16 bf16x8 __attribute__((ext_vector_type(8)));
typedef float  f32x4  __attribute__((ext_vector_type(4)));

#define BATCH 32
#define CIN   128
#define HH    56
#define WW    56
#define OC    256
#define HP    58
#define WP    58
#define PLANE  (HH*WW)    // 3136
#define KDIM   1152       // CIN*9
#define NT     18         // K tiles of 64 (KDIM/64)

#define XPAD_ELEMS (BATCH*HP*WP*CIN)   // NHWC padded bf16: 13,778,944
#define W3_ELEMS   (OC*KDIM)           // 294,912 bf16

#define GLDS16(g, l) __builtin_amdgcn_global_load_lds( \
    (const __attribute__((address_space(1))) void*)(g), \
    (__attribute__((address_space(3))) void*)(l), 16, 0, 0)

// ---- prep 0: zero top/bottom padded rows (h=0 and h=57 per image) ----
__global__ void zero_border(uint4* __restrict__ xp4) {
    int i = blockIdx.x * 256 + threadIdx.x;       // uint4 index
    if (i >= 64 * 928) return;                    // 64 rows x 928 uint4/row
    int row = i / 928;
    int off = i - row * 928;
    int b = row >> 1;
    int h = (row & 1) ? (HP - 1) : 0;
    xp4[((size_t)(b * HP + h) * WP * CIN) / 8 + off] = (uint4){0, 0, 0, 0};
}

// ---- prep 1: NCHW fp32 -> NHWC bf16, interior + left/right borders ----
// float2-vectorized gather (G13): 14 iters of 256 threads = 128c x 28 w-pairs
__global__ __launch_bounds__(256) void pad_tr(const float* __restrict__ x,
                                              u16* __restrict__ xpad) {
    __shared__ u16 T16[56 * 130];   // [w][c], +2 pad -> bank stride 65 dwords
    const int h = blockIdx.x;
    const int b = blockIdx.y;
    const int tid = threadIdx.x;

    const float* src = x + (size_t)b * CIN * PLANE + h * WW;
#pragma unroll
    for (int j = 0; j < 14; ++j) {              // 14*256 = 3584 = 128*28
        int flat = j * 256 + tid;
        int c  = flat / 28;
        int wp = flat - c * 28;
        int w  = wp * 2;
        float2 v = *(const float2*)&src[(size_t)c * PLANE + w];
        __hip_bfloat16 b0 = __float2bfloat16(v.x);
        __hip_bfloat16 b1 = __float2bfloat16(v.y);
        T16[w * 130 + c]       = *(u16*)&b0;
        T16[(w + 1) * 130 + c] = *(u16*)&b1;
    }
    __syncthreads();

    const u32* T32 = (const u32*)T16;
    uint4* dst = (uint4*)(xpad + (size_t)(b * HP + h + 1) * WP * CIN);
#pragma unroll
    for (int j = 0; j < 4; ++j) {
        int g = j * 256 + tid;
        if (g < 928) {
            int wp = g >> 4, cq = g & 15;       // 16 uint4 = 128 ch per wp
            uint4 v = (uint4){0, 0, 0, 0};
            if (wp >= 1 && wp <= 56) {
                int w = wp - 1;
                v.x = T32[w * 65 + cq * 4 + 0];
                v.y = T32[w * 65 + cq * 4 + 1];
                v.z = T32[w * 65 + cq * 4 + 2];
                v.w = T32[w * 65 + cq * 4 + 3];
            }
            dst[g] = v;
        }
    }
}

// ---- prep 2: W[OC][C*9] fp32 -> bf16, layout [T=18][oc 256][64k], rotation
// rot = row & 7 PRE-APPLIED (row = oc&127): position p stores true chunk
// ((p - rot) & 7).  128-B LDS rows start at bank 0 every row, so rotation
// must advance EVERY row.
__global__ void pack_w(const float* __restrict__ W, u16* __restrict__ w3) {
    int o = blockIdx.x * blockDim.x + threadIdx.x;
    if (o >= W3_ELEMS) return;
    int T   = o >> 14;            // /16384
    int rem = o & 16383;
    int oc  = rem >> 6;
    int kk  = rem & 63;
    int p   = kk >> 3;
    int e   = kk & 7;
    int rot = oc & 7;             // row within half = oc&127; rot = row&7
    int c64 = ((p - rot) & 7) * 8 + e;
    int r   = T >> 1;
    int c128 = (T & 1) * 64 + c64;
    float val = W[oc * KDIM + c128 * 9 + r];
    __hip_bfloat16 bv = __float2bfloat16(val);
    w3[o] = *(u16*)&bv;
}

// ---------------- main: implicit GEMM, 256x256 tile, BK=64 ------------------
// LOOKAHEAD schedule (r4): each MFMA cluster consumes fragments whose
// ds_reads were issued UNDER the previous cluster's MFMA, so the LDS read
// drain overlaps compute instead of serializing with it (r2 == r3 showed the
// serial {wait -> MFMA -> barrier} phase was the invariant cost ~1390 cyc).
//   P4(t): stage Wh1(t+2); vmcnt(6); BAR(C); ISSUE xlo(t+1) [8 rd];
//          cluster4 = W1X1(t) (regs only)     [xlo drains under cluster4]
//   P1(t): issue wlo,whi(t) [8 rd]; stage (t+1).Xh1; lgkm(4) [xlo+wlo done,
//          whi in flight]; cluster1 = W0X0; BAR(A)
//   P2(t): stage Wh0(t+2); issue xhi(t) [8 rd]; lgkm(8) [whi done];
//          cluster2 = W1X0                    [xhi drains under cluster2]
//   P3(t): stage Xh0(t+2); lgkm(0) [xhi done]; cluster3 = W0X1; BAR(B)
// WAR guards: BAR(A) covers P2's Wh0-stage (wlo reads done at lgkm(4)) and
// P3's Xh0-stage (xlo done at lgkm(4)); BAR(B) covers P4's Wh1-stage (whi
// done at P2's lgkm(8)); BAR(C) covers P1's Xh1-stage (xhi(t-1) done at
// P3(t-1) lgkm(0)) and makes tile t+1's DMA visible before xlo(t+1) reads.
// vmcnt(6) at P4: drains exactly through tile t+1's 8 loads, leaves the 3
// newest half-tiles (6 loads) in flight — never 0 in steady state.
// Only xlo is loop-carried (whi/xhi die in-iteration): live frags at
// cluster4 = 20 (80 VGPR) + acc 128 -> fits 256-VGPR @ 2 waves/SIMD.
// LDS rows 128 B = 32 banks; chunk-rotation rot = row & 7 keeps every
// ds_read_b128 conflict-free (verified: SQ_LDS_BANK_CONFLICT = 0).
__global__ __launch_bounds__(512, 2) void conv_main(
    const u16* __restrict__ xpad,
    const u16* __restrict__ w3,
    const float* __restrict__ bias,
    float* __restrict__ out)
{
    __shared__ __align__(16) u16 WL[2 * 2 * 128 * 64];  // [buf][half][128][64] 64KB
    __shared__ __align__(16) u16 XL[2 * 2 * 128 * 64];  // 64KB

    const int tid  = threadIdx.x;
    const int lane = tid & 63;
    const int wv   = tid >> 6;
    const int wm   = wv >> 2;       // spatial 64-row slice within each half
    const int wn   = wv & 3;        // oc 32-col slice within each half
    const int l16  = lane & 15;
    const int quad = lane >> 4;

    // XCD-aware swizzle: 392 = 8 * 49 (divisible -> simple form is bijective)
    const int bid  = blockIdx.x;
    const int tile = (bid & 7) * 49 + (bid >> 3);
    const int m0   = tile * 256;

    // ---- staging geometry: instr i covers rows (wv*2+i)*8..+7, pos lane&7 ----
    const int srow8 = lane >> 3;
    const int spos  = lane & 7;
    size_t xsrc[2][2];
#pragma unroll
    for (int h = 0; h < 2; ++h)
#pragma unroll
        for (int i = 0; i < 2; ++i) {
            int r  = (wv * 2 + i) * 8 + srow8;          // row within half
            int q  = (spos - (r & 7)) & 7;              // source chunk (r&7=srow8)
            int m  = m0 + h * 128 + r;
            int b  = m / PLANE;
            int s  = m - b * PLANE;
            int hh = s / WW;
            int ww = s - hh * WW;
            xsrc[h][i] = ((size_t)((b * HP + hh) * WP + ww) * CIN) * 2 + (size_t)q * 16;
        }
    const char* xb  = (const char*)xpad;
    const char* w3b = (const char*)w3;
    const int dstat     = wv * 2048;            // LDS dst (wave-uniform) base
    const int wsrc_lane = wv * 2048 + lane * 16;

    auto xkoff = [&](int kt) -> int {
        int r9 = kt >> 1;
        int kh = (r9 * 11) >> 5;                // r9/3 for r9 in 0..8
        int kw = r9 - kh * 3;
        return ((kh * WP + kw) * CIN + (kt & 1) * 64) * 2;
    };
    auto stageW = [&](int kt, int h) {
        const char* src = w3b + (size_t)kt * 32768 + h * 16384 + wsrc_lane;
        char* dst = (char*)WL + (kt & 1) * 32768 + h * 16384 + dstat;
        GLDS16(src,        dst);
        GLDS16(src + 1024, dst + 1024);
    };
    auto stageX = [&](int kt, int h, int xko) {
        char* dst = (char*)XL + (kt & 1) * 32768 + h * 16384 + dstat;
        GLDS16(xb + xsrc[h][0] + xko, dst);
        GLDS16(xb + xsrc[h][1] + xko, dst + 1024);
    };

    // frag ds_read byte offsets within a half-slot (s=0; s=1 is ^64)
    int woff[2], xoff[4];
#pragma unroll
    for (int j = 0; j < 2; ++j) {
        int r = wn * 32 + j * 16 + l16;
        woff[j] = r * 128 + (((quad + r) & 7) << 4);
    }
#pragma unroll
    for (int j = 0; j < 4; ++j) {
        int r = wm * 64 + j * 16 + l16;
        xoff[j] = r * 128 + (((quad + r) & 7) << 4);
    }

    f32x4 acc[4][8];
#pragma unroll
    for (int f = 0; f < 4; ++f) {
        const int ob = (f >> 1) * 128 + wn * 32 + (f & 1) * 16 + quad * 4;
        f32x4 bv = *(const f32x4*)&bias[ob];
#pragma unroll
        for (int g = 0; g < 8; ++g) acc[f][g] = bv;
    }

    // ---- prologue: tile0 full + tile1 {Wh0,Xh0,Wh1} (14 loads in flight) ----
    stageW(0, 0); stageW(0, 1);
    stageX(0, 0, xkoff(0)); stageX(0, 1, xkoff(0));
    stageW(1, 0); stageX(1, 0, xkoff(1)); stageW(1, 1);
    asm volatile("s_waitcnt vmcnt(6)" ::: "memory");   // tile0's 8 loads landed
    __builtin_amdgcn_sched_barrier(0);
    __builtin_amdgcn_s_barrier();
    __builtin_amdgcn_sched_barrier(0);

    // loop-carried: xlo(0) reads issued here, consumed by cluster1 of kt=0
    bf16x8 xlo[4][2];
#pragma unroll
    for (int j = 0; j < 4; ++j) {
        xlo[j][0] = *(const bf16x8*)((const char*)XL + xoff[j]);
        xlo[j][1] = *(const bf16x8*)((const char*)XL + (xoff[j] ^ 64));
    }

#pragma unroll 1
    for (int kt = 0; kt < NT; ++kt) {
        const char* Wb  = (const char*)WL + (kt & 1) * 32768;
        const char* Xb  = (const char*)XL + (kt & 1) * 32768;
        const char* Xbn = (const char*)XL + ((kt + 1) & 1) * 32768;
        const bool st2 = (kt + 2 < NT);

        // ===== P1: issue wlo,whi; stage (t+1).Xh1; lgkm(4); cluster1 W0X0 ====
        bf16x8 wlo[2][2], whi[2][2];
#pragma unroll
        for (int j = 0; j < 2; ++j) {
            wlo[j][0] = *(const bf16x8*)(Wb + woff[j]);
            wlo[j][1] = *(const bf16x8*)(Wb + (woff[j] ^ 64));
        }
#pragma unroll
        for (int j = 0; j < 2; ++j) {
            whi[j][0] = *(const bf16x8*)(Wb + 16384 + woff[j]);
            whi[j][1] = *(const bf16x8*)(Wb + 16384 + (woff[j] ^ 64));
        }
        __builtin_amdgcn_sched_barrier(0);
        if (kt + 1 < NT) stageX(kt + 1, 1, xkoff(kt + 1));
        asm volatile("s_waitcnt lgkmcnt(4)" ::: "memory");  // xlo+wlo landed
        __builtin_amdgcn_sched_barrier(0);
        __builtin_amdgcn_s_setprio(1);
#pragma unroll
        for (int f = 0; f < 2; ++f)
#pragma unroll
            for (int g = 0; g < 4; ++g)
#pragma unroll
                for (int s = 0; s < 2; ++s)
                    acc[f][g] = __builtin_amdgcn_mfma_f32_16x16x32_bf16(
                        wlo[f][s], xlo[g][s], acc[f][g], 0, 0, 0);
        __builtin_amdgcn_s_setprio(0);
        __builtin_amdgcn_s_barrier();           // BAR(A): wlo+xlo reads done

        // ===== P2: stage Wh0(t+2); issue xhi; lgkm(8); cluster2 W1X0 =====
        if (st2) stageW(kt + 2, 0);
        bf16x8 xhi[4][2];
#pragma unroll
        for (int j = 0; j < 4; ++j) {
            xhi[j][0] = *(const bf16x8*)(Xb + 16384 + xoff[j]);
            xhi[j][1] = *(const bf16x8*)(Xb + 16384 + (xoff[j] ^ 64));
        }
        __builtin_amdgcn_sched_barrier(0);
        asm volatile("s_waitcnt lgkmcnt(8)" ::: "memory");  // whi landed
        __builtin_amdgcn_sched_barrier(0);
        __builtin_amdgcn_s_setprio(1);
#pragma unroll
        for (int f = 0; f < 2; ++f)
#pragma unroll
            for (int g = 0; g < 4; ++g)
#pragma unroll
                for (int s = 0; s < 2; ++s)
                    acc[2 + f][g] = __builtin_amdgcn_mfma_f32_16x16x32_bf16(
                        whi[f][s], xlo[g][s], acc[2 + f][g], 0, 0, 0);
        __builtin_amdgcn_s_setprio(0);
        // no barrier: P3's stage hits slot Xh0 (reads done pre-BAR(A))

        // ===== P3: stage Xh0(t+2); lgkm(0) -> xhi; cluster3 W0X1 =====
        if (st2) stageX(kt + 2, 0, xkoff(kt + 2));
        asm volatile("s_waitcnt lgkmcnt(0)" ::: "memory");
        __builtin_amdgcn_sched_barrier(0);
        __builtin_amdgcn_s_setprio(1);
#pragma unroll
        for (int f = 0; f < 2; ++f)
#pragma unroll
            for (int g = 0; g < 4; ++g)
#pragma unroll
                for (int s = 0; s < 2; ++s)
                    acc[f][4 + g] = __builtin_amdgcn_mfma_f32_16x16x32_bf16(
                        wlo[f][s], xhi[g][s], acc[f][4 + g], 0, 0, 0);
        __builtin_amdgcn_s_setprio(0);
        __builtin_amdgcn_s_barrier();           // BAR(B): whi reads done

        // ===== P4: stage Wh1(t+2); vmcnt; BAR(C); ISSUE xlo(t+1); cluster4 ==
        if (st2) stageW(kt + 2, 1);
        // counted drain: steady state keeps 3 half-tiles (6 loads) in flight;
        // at kt>=NT-2 nothing newer was issued -> drain fully.
        if (kt < NT - 2) asm volatile("s_waitcnt vmcnt(6)" ::: "memory");
        else             asm volatile("s_waitcnt vmcnt(0)" ::: "memory");
        __builtin_amdgcn_sched_barrier(0);
        __builtin_amdgcn_s_barrier();           // BAR(C): tile t+1 visible
        __builtin_amdgcn_sched_barrier(0);
        if (kt + 1 < NT) {
#pragma unroll
            for (int j = 0; j < 4; ++j) {
                xlo[j][0] = *(const bf16x8*)(Xbn + xoff[j]);
                xlo[j][1] = *(const bf16x8*)(Xbn + (xoff[j] ^ 64));
            }
        }
        __builtin_amdgcn_s_setprio(1);
#pragma unroll
        for (int f = 0; f < 2; ++f)
#pragma unroll
            for (int g = 0; g < 4; ++g)
#pragma unroll
                for (int s = 0; s < 2; ++s)
                    acc[2 + f][4 + g] = __builtin_amdgcn_mfma_f32_16x16x32_bf16(
                        whi[f][s], xhi[g][s], acc[2 + f][4 + g], 0, 0, 0);
        __builtin_amdgcn_s_setprio(0);
    }

    // ---- epilogue: D row = oc (quad*4+i), col = spatial (lane&15) ----
#pragma unroll
    for (int g = 0; g < 8; ++g) {
        const int mm = m0 + (g >> 2) * 128 + wm * 64 + (g & 3) * 16 + l16;
        const int bb = mm / PLANE;
        const int ss = mm - bb * PLANE;
        float* obase = out + (size_t)bb * (OC * PLANE) + ss;
#pragma unroll
        for (int f = 0; f < 4; ++f) {
            const int n = (f >> 1) * 128 + wn * 32 + (f & 1) * 16 + quad * 4;
#pragma unroll
            for (int i = 0; i < 4; ++i)
                obase[(size_t)(n + i) * PLANE] = acc[f][g][i];
        }
    }
}

extern "C" void kernel_launch(void* const* d_in, const int* in_sizes, int n_in,
                              void* d_out, int out_size, void* d_ws, size_t ws_size,
                              hipStream_t stream) {
    const float* x    = (const float*)d_in[0];
    const float* W    = (const float*)d_in[1];
    const float* bias = (const float*)d_in[2];
    float* out = (float*)d_out;

    u16* xpad = (u16*)d_ws;
    u16* w3   = xpad + XPAD_ELEMS;

    zero_border<<<232, 256, 0, stream>>>((uint4*)xpad);
    pad_tr<<<dim3(HH, BATCH), 256, 0, stream>>>(x, xpad);
    pack_w<<<(W3_ELEMS + 255) / 256, 256, 0, stream>>>(W, w3);

    conv_main<<<392, 512, 0, stream>>>(xpad, w3, bias, out);
}

// Round 6
// 226.450 us; speedup vs baseline: 1.0081x; 1.0081x over previous
//
#include <hip/hip_runtime.h>
#include <hip/hip_bf16.h>
#include <stdint.h>

typedef unsigned short u16;
typedef unsigned int   u32;
typedef __bf16 bf16x8 __attribute__((ext_vector_type(8)));
typedef float  f32x4  __attribute__((ext_vector_type(4)));

#define BATCH 32
#define CIN   128
#define HH    56
#define WW    56
#define OC    256
#define HP    58
#define WP    58
#define PLANE  (HH*WW)    // 3136
#define KDIM   1152       // CIN*9
#define NT     18         // K tiles of 64 (KDIM/64)

#define XPAD_ELEMS (BATCH*HP*WP*CIN)   // NHWC padded bf16: 13,778,944
#define W3_ELEMS   (OC*KDIM)           // 294,912 bf16

#define GLDS16(g, l) __builtin_amdgcn_global_load_lds( \
    (const __attribute__((address_space(1))) void*)(g), \
    (__attribute__((address_space(3))) void*)(l), 16, 0, 0)

// ---- prep 0: zero top/bottom padded rows (h=0 and h=57 per image) ----
__global__ void zero_border(uint4* __restrict__ xp4) {
    int i = blockIdx.x * 256 + threadIdx.x;       // uint4 index
    if (i >= 64 * 928) return;                    // 64 rows x 928 uint4/row
    int row = i / 928;
    int off = i - row * 928;
    int b = row >> 1;
    int h = (row & 1) ? (HP - 1) : 0;
    xp4[((size_t)(b * HP + h) * WP * CIN) / 8 + off] = (uint4){0, 0, 0, 0};
}

// ---- prep 1: NCHW fp32 -> NHWC bf16, interior + left/right borders ----
// float2-vectorized gather (G13): 14 iters of 256 threads = 128c x 28 w-pairs
__global__ __launch_bounds__(256) void pad_tr(const float* __restrict__ x,
                                              u16* __restrict__ xpad) {
    __shared__ u16 T16[56 * 130];   // [w][c], +2 pad -> bank stride 65 dwords
    const int h = blockIdx.x;
    const int b = blockIdx.y;
    const int tid = threadIdx.x;

    const float* src = x + (size_t)b * CIN * PLANE + h * WW;
#pragma unroll
    for (int j = 0; j < 14; ++j) {              // 14*256 = 3584 = 128*28
        int flat = j * 256 + tid;
        int c  = flat / 28;
        int wp = flat - c * 28;
        int w  = wp * 2;
        float2 v = *(const float2*)&src[(size_t)c * PLANE + w];
        __hip_bfloat16 b0 = __float2bfloat16(v.x);
        __hip_bfloat16 b1 = __float2bfloat16(v.y);
        T16[w * 130 + c]       = *(u16*)&b0;
        T16[(w + 1) * 130 + c] = *(u16*)&b1;
    }
    __syncthreads();

    const u32* T32 = (const u32*)T16;
    uint4* dst = (uint4*)(xpad + (size_t)(b * HP + h + 1) * WP * CIN);
#pragma unroll
    for (int j = 0; j < 4; ++j) {
        int g = j * 256 + tid;
        if (g < 928) {
            int wp = g >> 4, cq = g & 15;       // 16 uint4 = 128 ch per wp
            uint4 v = (uint4){0, 0, 0, 0};
            if (wp >= 1 && wp <= 56) {
                int w = wp - 1;
                v.x = T32[w * 65 + cq * 4 + 0];
                v.y = T32[w * 65 + cq * 4 + 1];
                v.z = T32[w * 65 + cq * 4 + 2];
                v.w = T32[w * 65 + cq * 4 + 3];
            }
            dst[g] = v;
        }
    }
}

// ---- prep 2: W[OC][C*9] fp32 -> bf16, layout [T=18][oc 256][64k], rotation
// rot = row & 7 PRE-APPLIED (row = oc&127): position p stores true chunk
// ((p - rot) & 7).  128-B LDS rows start at bank 0 every row, so rotation
// must advance EVERY row.
__global__ void pack_w(const float* __restrict__ W, u16* __restrict__ w3) {
    int o = blockIdx.x * blockDim.x + threadIdx.x;
    if (o >= W3_ELEMS) return;
    int T   = o >> 14;            // /16384
    int rem = o & 16383;
    int oc  = rem >> 6;
    int kk  = rem & 63;
    int p   = kk >> 3;
    int e   = kk & 7;
    int rot = oc & 7;             // row within half = oc&127; rot = row&7
    int c64 = ((p - rot) & 7) * 8 + e;
    int r   = T >> 1;
    int c128 = (T & 1) * 64 + c64;
    float val = W[oc * KDIM + c128 * 9 + r];
    __hip_bfloat16 bv = __float2bfloat16(val);
    w3[o] = *(u16*)&bv;
}

// ---------------- main: implicit GEMM, 256x256 tile, BK=64 ------------------
// UNPINNED schedule (r5): the r2/r3/r4 variants all hand-pinned instruction
// order with sched_barrier(0) walls + blunt lgkmcnt asm and all landed at
// ~1390 cyc/phase — the m141 failure mode (order-pinning defeats the
// compiler's fine-grained lgkmcnt(4/3/1/0) read/MFMA interleave, m97).
// This version keeps ONLY the semantically required sync:
//   - 3 s_barriers/kt (WAR guards for LDS slot reuse)
//   - 1 counted vmcnt(6)/kt (DMA visibility; never 0 in steady state)
//   - setprio around MFMA clusters
// and lets the compiler schedule ds_reads, glds issue, and MFMAs freely.
// WAR correctness (DS retires in order; compiler RAW waits before each MFMA
// retire that phase's reads before the phase's trailing barrier):
//   BAR(A): wlo+xlo reads retired (consumed by cluster1) -> stage Wh0(t+2)
//           and stage Xh0(t+2) safe after it
//   BAR(B): whi reads retired (consumed by cluster2)     -> stage Wh1(t+2)
//   BAR(C): vmcnt(6) drained through tile t+1's 8 loads  -> next iter's
//           frag reads see valid data; xhi retired (cluster3 < BAR(B))
//           covers the Xh1(t+2) stage issued next iter after BAR(C)
// LDS rows 128 B = 32 banks; chunk-rotation rot = row & 7 keeps every
// ds_read_b128 conflict-free (verified: SQ_LDS_BANK_CONFLICT = 0).
__global__ __launch_bounds__(512, 2) void conv_main(
    const u16* __restrict__ xpad,
    const u16* __restrict__ w3,
    const float* __restrict__ bias,
    float* __restrict__ out)
{
    __shared__ __align__(16) u16 WL[2 * 2 * 128 * 64];  // [buf][half][128][64] 64KB
    __shared__ __align__(16) u16 XL[2 * 2 * 128 * 64];  // 64KB

    const int tid  = threadIdx.x;
    const int lane = tid & 63;
    const int wv   = tid >> 6;
    const int wm   = wv >> 2;       // spatial 64-row slice within each half
    const int wn   = wv & 3;        // oc 32-col slice within each half
    const int l16  = lane & 15;
    const int quad = lane >> 4;

    // XCD-aware swizzle: 392 = 8 * 49 (divisible -> simple form is bijective)
    const int bid  = blockIdx.x;
    const int tile = (bid & 7) * 49 + (bid >> 3);
    const int m0   = tile * 256;

    // ---- staging geometry: instr i covers rows (wv*2+i)*8..+7, pos lane&7 ----
    const int srow8 = lane >> 3;
    const int spos  = lane & 7;
    size_t xsrc[2][2];
#pragma unroll
    for (int h = 0; h < 2; ++h)
#pragma unroll
        for (int i = 0; i < 2; ++i) {
            int r  = (wv * 2 + i) * 8 + srow8;          // row within half
            int q  = (spos - (r & 7)) & 7;              // source chunk (r&7=srow8)
            int m  = m0 + h * 128 + r;
            int b  = m / PLANE;
            int s  = m - b * PLANE;
            int hh = s / WW;
            int ww = s - hh * WW;
            xsrc[h][i] = ((size_t)((b * HP + hh) * WP + ww) * CIN) * 2 + (size_t)q * 16;
        }
    const char* xb  = (const char*)xpad;
    const char* w3b = (const char*)w3;
    const int dstat     = wv * 2048;            // LDS dst (wave-uniform) base
    const int wsrc_lane = wv * 2048 + lane * 16;

    auto xkoff = [&](int kt) -> int {
        int r9 = kt >> 1;
        int kh = (r9 * 11) >> 5;                // r9/3 for r9 in 0..8
        int kw = r9 - kh * 3;
        return ((kh * WP + kw) * CIN + (kt & 1) * 64) * 2;
    };
    auto stageW = [&](int kt, int h) {
        const char* src = w3b + (size_t)kt * 32768 + h * 16384 + wsrc_lane;
        char* dst = (char*)WL + (kt & 1) * 32768 + h * 16384 + dstat;
        GLDS16(src,        dst);
        GLDS16(src + 1024, dst + 1024);
    };
    auto stageX = [&](int kt, int h, int xko) {
        char* dst = (char*)XL + (kt & 1) * 32768 + h * 16384 + dstat;
        GLDS16(xb + xsrc[h][0] + xko, dst);
        GLDS16(xb + xsrc[h][1] + xko, dst + 1024);
    };

    // frag ds_read byte offsets within a half-slot (s=0; s=1 is ^64)
    int woff[2], xoff[4];
#pragma unroll
    for (int j = 0; j < 2; ++j) {
        int r = wn * 32 + j * 16 + l16;
        woff[j] = r * 128 + (((quad + r) & 7) << 4);
    }
#pragma unroll
    for (int j = 0; j < 4; ++j) {
        int r = wm * 64 + j * 16 + l16;
        xoff[j] = r * 128 + (((quad + r) & 7) << 4);
    }

    f32x4 acc[4][8];
#pragma unroll
    for (int f = 0; f < 4; ++f) {
        const int ob = (f >> 1) * 128 + wn * 32 + (f & 1) * 16 + quad * 4;
        f32x4 bv = *(const f32x4*)&bias[ob];
#pragma unroll
        for (int g = 0; g < 8; ++g) acc[f][g] = bv;
    }

    // ---- prologue: tile0 full + tile1 {Wh0,Xh0,Wh1} (14 loads in flight) ----
    stageW(0, 0); stageW(0, 1);
    stageX(0, 0, xkoff(0)); stageX(0, 1, xkoff(0));
    stageW(1, 0); stageX(1, 0, xkoff(1)); stageW(1, 1);
    asm volatile("s_waitcnt vmcnt(6)" ::: "memory");   // tile0's 8 loads landed
    __builtin_amdgcn_s_barrier();

#pragma unroll 1
    for (int kt = 0; kt < NT; ++kt) {
        const char* Wb = (const char*)WL + (kt & 1) * 32768;
        const char* Xb = (const char*)XL + (kt & 1) * 32768;
        const bool st2 = (kt + 2 < NT);

        // ===== phase A: wlo+xlo reads; stage (t+1).Xh1; cluster1 W0X0 =====
        bf16x8 wlo[2][2], xlo[4][2];
#pragma unroll
        for (int j = 0; j < 2; ++j) {
            wlo[j][0] = *(const bf16x8*)(Wb + woff[j]);
            wlo[j][1] = *(const bf16x8*)(Wb + (woff[j] ^ 64));
        }
#pragma unroll
        for (int j = 0; j < 4; ++j) {
            xlo[j][0] = *(const bf16x8*)(Xb + xoff[j]);
            xlo[j][1] = *(const bf16x8*)(Xb + (xoff[j] ^ 64));
        }
        if (kt + 1 < NT) stageX(kt + 1, 1, xkoff(kt + 1));
        __builtin_amdgcn_s_setprio(1);
#pragma unroll
        for (int f = 0; f < 2; ++f)
#pragma unroll
            for (int g = 0; g < 4; ++g)
#pragma unroll
                for (int s = 0; s < 2; ++s)
                    acc[f][g] = __builtin_amdgcn_mfma_f32_16x16x32_bf16(
                        wlo[f][s], xlo[g][s], acc[f][g], 0, 0, 0);
        __builtin_amdgcn_s_setprio(0);
        __builtin_amdgcn_s_barrier();           // BAR(A): wlo+xlo retired

        // ===== phase B: stage Wh0(t+2); whi reads; cluster2 W1X0 =====
        if (st2) stageW(kt + 2, 0);
        bf16x8 whi[2][2];
#pragma unroll
        for (int j = 0; j < 2; ++j) {
            whi[j][0] = *(const bf16x8*)(Wb + 16384 + woff[j]);
            whi[j][1] = *(const bf16x8*)(Wb + 16384 + (woff[j] ^ 64));
        }
        __builtin_amdgcn_s_setprio(1);
#pragma unroll
        for (int f = 0; f < 2; ++f)
#pragma unroll
            for (int g = 0; g < 4; ++g)
#pragma unroll
                for (int s = 0; s < 2; ++s)
                    acc[2 + f][g] = __builtin_amdgcn_mfma_f32_16x16x32_bf16(
                        whi[f][s], xlo[g][s], acc[2 + f][g], 0, 0, 0);
        __builtin_amdgcn_s_setprio(0);

        // ===== phase C: stage Xh0(t+2); xhi reads; cluster3 W0X1 =====
        if (st2) stageX(kt + 2, 0, xkoff(kt + 2));
        bf16x8 xhi[4][2];
#pragma unroll
        for (int j = 0; j < 4; ++j) {
            xhi[j][0] = *(const bf16x8*)(Xb + 16384 + xoff[j]);
            xhi[j][1] = *(const bf16x8*)(Xb + 16384 + (xoff[j] ^ 64));
        }
        __builtin_amdgcn_s_setprio(1);
#pragma unroll
        for (int f = 0; f < 2; ++f)
#pragma unroll
            for (int g = 0; g < 4; ++g)
#pragma unroll
                for (int s = 0; s < 2; ++s)
                    acc[f][4 + g] = __builtin_amdgcn_mfma_f32_16x16x32_bf16(
                        wlo[f][s], xhi[g][s], acc[f][4 + g], 0, 0, 0);
        __builtin_amdgcn_s_setprio(0);
        __builtin_amdgcn_s_barrier();           // BAR(B): whi retired

        // ===== phase D: stage Wh1(t+2); cluster4 W1X1 (regs); vmcnt; BAR(C) ==
        if (st2) stageW(kt + 2, 1);
        __builtin_amdgcn_s_setprio(1);
#pragma unroll
        for (int f = 0; f < 2; ++f)
#pragma unroll
            for (int g = 0; g < 4; ++g)
#pragma unroll
                for (int s = 0; s < 2; ++s)
                    acc[2 + f][4 + g] = __builtin_amdgcn_mfma_f32_16x16x32_bf16(
                        whi[f][s], xhi[g][s], acc[2 + f][4 + g], 0, 0, 0);
        __builtin_amdgcn_s_setprio(0);
        // counted drain: steady state keeps 3 half-tiles (6 loads) in flight;
        // at kt>=NT-2 nothing newer was issued -> drain fully.
        if (kt < NT - 2) asm volatile("s_waitcnt vmcnt(6)" ::: "memory");
        else             asm volatile("s_waitcnt vmcnt(0)" ::: "memory");
        __builtin_amdgcn_s_barrier();           // BAR(C): tile t+1 visible
    }

    // ---- epilogue: D row = oc (quad*4+i), col = spatial (lane&15) ----
#pragma unroll
    for (int g = 0; g < 8; ++g) {
        const int mm = m0 + (g >> 2) * 128 + wm * 64 + (g & 3) * 16 + l16;
        const int bb = mm / PLANE;
        const int ss = mm - bb * PLANE;
        float* obase = out + (size_t)bb * (OC * PLANE) + ss;
#pragma unroll
        for (int f = 0; f < 4; ++f) {
            const int n = (f >> 1) * 128 + wn * 32 + (f & 1) * 16 + quad * 4;
#pragma unroll
            for (int i = 0; i < 4; ++i)
                obase[(size_t)(n + i) * PLANE] = acc[f][g][i];
        }
    }
}

extern "C" void kernel_launch(void* const* d_in, const int* in_sizes, int n_in,
                              void* d_out, int out_size, void* d_ws, size_t ws_size,
                              hipStream_t stream) {
    const float* x    = (const float*)d_in[0];
    const float* W    = (const float*)d_in[1];
    const float* bias = (const float*)d_in[2];
    float* out = (float*)d_out;

    u16* xpad = (u16*)d_ws;
    u16* w3   = xpad + XPAD_ELEMS;

    zero_border<<<232, 256, 0, stream>>>((uint4*)xpad);
    pad_tr<<<dim3(HH, BATCH), 256, 0, stream>>>(x, xpad);
    pack_w<<<(W3_ELEMS + 255) / 256, 256, 0, stream>>>(W, w3);

    conv_main<<<392, 512, 0, stream>>>(xpad, w3, bias, out);
}

// Round 7
// 216.762 us; speedup vs baseline: 1.0531x; 1.0447x over previous
//
#include <hip/hip_runtime.h>
#include <hip/hip_bf16.h>
#include <stdint.h>

typedef unsigned short u16;
typedef unsigned int   u32;
typedef __bf16 bf16x8 __attribute__((ext_vector_type(8)));
typedef float  f32x4  __attribute__((ext_vector_type(4)));

#define BATCH 32
#define CIN   128
#define HH    56
#define WW    56
#define OC    256
#define HP    58
#define WP    58
#define PLANE  (HH*WW)    // 3136
#define KDIM   1152       // CIN*9
#define NT     36         // K tiles of 32 (KDIM/32)

#define XPAD_ELEMS (BATCH*HP*WP*CIN)   // NHWC padded bf16: 13,778,944
#define W3_ELEMS   (OC*KDIM)           // 294,912 bf16

#define GLDS16(g, l) __builtin_amdgcn_global_load_lds( \
    (const __attribute__((address_space(1))) void*)(g), \
    (__attribute__((address_space(3))) void*)(l), 16, 0, 0)

// ---- prep 0: zero top/bottom padded rows (h=0 and h=57 per image) ----
__global__ void zero_border(uint4* __restrict__ xp4) {
    int i = blockIdx.x * 256 + threadIdx.x;       // uint4 index
    if (i >= 64 * 928) return;                    // 64 rows x 928 uint4/row
    int row = i / 928;
    int off = i - row * 928;
    int b = row >> 1;
    int h = (row & 1) ? (HP - 1) : 0;
    xp4[((size_t)(b * HP + h) * WP * CIN) / 8 + off] = (uint4){0, 0, 0, 0};
}

// ---- prep 1: NCHW fp32 -> NHWC bf16, interior + left/right borders ----
__global__ __launch_bounds__(256) void pad_tr(const float* __restrict__ x,
                                              u16* __restrict__ xpad) {
    __shared__ u16 T16[56 * 130];   // [w][c], +2 pad -> bank stride 65 dwords
    const int h = blockIdx.x;
    const int b = blockIdx.y;
    const int tid = threadIdx.x;

    const float* src = x + (size_t)b * CIN * PLANE + h * WW;
#pragma unroll
    for (int j = 0; j < 14; ++j) {              // 14*256 = 3584 = 128*28
        int flat = j * 256 + tid;
        int c  = flat / 28;
        int wp = flat - c * 28;
        int w  = wp * 2;
        float2 v = *(const float2*)&src[(size_t)c * PLANE + w];
        __hip_bfloat16 b0 = __float2bfloat16(v.x);
        __hip_bfloat16 b1 = __float2bfloat16(v.y);
        T16[w * 130 + c]       = *(u16*)&b0;
        T16[(w + 1) * 130 + c] = *(u16*)&b1;
    }
    __syncthreads();

    const u32* T32 = (const u32*)T16;
    uint4* dst = (uint4*)(xpad + (size_t)(b * HP + h + 1) * WP * CIN);
#pragma unroll
    for (int j = 0; j < 4; ++j) {
        int g = j * 256 + tid;
        if (g < 928) {
            int wp = g >> 4, cq = g & 15;       // 16 uint4 = 128 ch per wp
            uint4 v = (uint4){0, 0, 0, 0};
            if (wp >= 1 && wp <= 56) {
                int w = wp - 1;
                v.x = T32[w * 65 + cq * 4 + 0];
                v.y = T32[w * 65 + cq * 4 + 1];
                v.z = T32[w * 65 + cq * 4 + 2];
                v.w = T32[w * 65 + cq * 4 + 3];
            }
            dst[g] = v;
        }
    }
}

// ---- prep 2: W[OC][C*9] fp32 -> bf16, layout [T=36][oc 256][k 32], with the
// 64B-row 4-chunk rotation PRE-APPLIED (r0's proven-conflict-free scheme):
// row = oc, rot = (row>>1)&3; LDS position p stores true chunk ((p - rot)&3).
// K-tile T covers r = T>>2 (kh*3+kw), channel quarter cq = T&3 (32 ch).
__global__ void pack_w(const float* __restrict__ W, u16* __restrict__ w3) {
    int o = blockIdx.x * blockDim.x + threadIdx.x;
    if (o >= W3_ELEMS) return;
    int T   = o >> 13;            // /8192 (256 oc x 32 k)
    int rem = o & 8191;
    int oc  = rem >> 5;
    int kk  = rem & 31;
    int p   = kk >> 3;            // chunk position 0..3
    int e   = kk & 7;
    int rot = (oc >> 1) & 3;
    int c32 = ((p - rot) & 3) * 8 + e;
    int r   = T >> 2;             // 0..8
    int c128 = (T & 3) * 32 + c32;
    float val = W[oc * KDIM + c128 * 9 + r];
    __hip_bfloat16 bv = __float2bfloat16(val);
    w3[o] = *(u16*)&bv;
}

// ---------------- main: implicit GEMM, 128x256 tile, BK=32 ------------------
// OCCUPANCY-FIRST (r6): the 256-sq/1-block-per-CU family (r2-r5) spanned
// 83-98 us across 4 schedule permutations -> schedule is not the binding
// variable; the missing ingredient is co-resident blocks (m114 cross-block
// overlap: an independent block's waves fill the SIMD while this block sits
// at its barrier/drain).  This kernel: 48 KB LDS, 256 threads, ~200 VGPR ->
// 2-3 blocks/CU, with r0's PROVEN minimal schedule (one __syncthreads per
// kt, DMA(kt+1) issued after barrier(kt), overlapped by compute(kt)) and
// r0's PROVEN 64B-row rotation swizzle (0 bank conflicts measured).
// vs r0 it keeps the 256-sq family's wins: BN=256 = full OC so X is staged
// ONCE (FETCH 64.6 -> ~18 MB) and per-wave read ratio 0.0229 B/FLOP.
// 4 waves = 4 oc-slices of 64; per-wave output 64oc x 128sp; acc[4][8];
// one MFMA per acc per kt (K=32) -> all 32 MFMAs independent (no RAW).
// Grid 784 = 8*98 -> bijective XCD swizzle; no global round barrier.
__global__ __launch_bounds__(256, 2) void conv_main(
    const u16* __restrict__ xpad,
    const u16* __restrict__ w3,
    const float* __restrict__ bias,
    float* __restrict__ out)
{
    __shared__ __align__(16) u16 WL[2][256 * 32];  // 16 KB each: [oc][k32]
    __shared__ __align__(16) u16 XL[2][128 * 32];  //  8 KB each: [sp][k32]

    const int tid  = threadIdx.x;
    const int lane = tid & 63;
    const int wv   = tid >> 6;      // wave = oc slice (64 oc each)
    const int l16  = lane & 15;
    const int quad = lane >> 4;

    // XCD-aware swizzle: 784 = 8 * 98 (divisible -> bijective)
    const int bid  = blockIdx.x;
    const int tile = (bid & 7) * 98 + (bid >> 3);
    const int m0   = tile * 128;

    // ---- X staging geometry: instr i covers rows i*64 + (tid>>2), pos tid&3
    const int srow = tid >> 2;      // 0..63
    const int spos = tid & 3;
    size_t xsrc[2];
#pragma unroll
    for (int i = 0; i < 2; ++i) {
        int r  = i * 64 + srow;                     // row 0..127
        int q  = (spos - ((r >> 1) & 3)) & 3;       // source chunk for rot
        int m  = m0 + r;
        int b  = m / PLANE;
        int s  = m - b * PLANE;
        int hh = s / WW;
        int ww = s - hh * WW;
        xsrc[i] = ((size_t)((b * HP + hh) * WP + ww) * CIN) * 2 + (size_t)q * 16;
    }
    const char* xb  = (const char*)xpad;
    const char* w3b = (const char*)w3;

    auto xkoff = [&](int kt) -> int {
        int r9 = kt >> 2;
        int kh = (r9 * 11) >> 5;                // r9/3 for r9 in 0..8
        int kw = r9 - kh * 3;
        return ((kh * WP + kw) * CIN + (kt & 3) * 32) * 2;
    };
    // one kt stage: W 16 KB (4 instr/thread, linear) + X 8 KB (2 instr/thread)
    auto issue = [&](int kt) {
        const int buf = kt & 1;
        const char* wsrc = w3b + (size_t)kt * 16384 + tid * 16;
        char* wdst = (char*)WL[buf] + tid * 16;
#pragma unroll
        for (int j = 0; j < 4; ++j)
            GLDS16(wsrc + j * 4096, wdst + j * 4096);
        const int xko = xkoff(kt);
        char* xdst = (char*)XL[buf] + tid * 16;
#pragma unroll
        for (int i = 0; i < 2; ++i)
            GLDS16(xb + xsrc[i] + xko, xdst + i * 4096);
    };

    // frag ds_read byte offsets (64B rows, rot = (r>>1)&3 — r0's scheme)
    int woff[4], xoff[8];
#pragma unroll
    for (int f = 0; f < 4; ++f) {
        int r = wv * 64 + f * 16 + l16;
        woff[f] = r * 64 + (((quad + (r >> 1)) & 3) << 4);
    }
#pragma unroll
    for (int g = 0; g < 8; ++g) {
        int r = g * 16 + l16;
        xoff[g] = r * 64 + (((quad + (r >> 1)) & 3) << 4);
    }

    f32x4 acc[4][8];
#pragma unroll
    for (int f = 0; f < 4; ++f) {
        f32x4 bv = *(const f32x4*)&bias[wv * 64 + f * 16 + quad * 4];
#pragma unroll
        for (int g = 0; g < 8; ++g) acc[f][g] = bv;
    }

    issue(0);
#pragma unroll 1
    for (int kt = 0; kt < NT; ++kt) {
        __syncthreads();                    // drains DMA(kt); frees other buf
        if (kt + 1 < NT) issue(kt + 1);     // in flight across compute(kt)

        const char* Wb = (const char*)WL[kt & 1];
        const char* Xb = (const char*)XL[kt & 1];
        bf16x8 wf[4], xf[8];
#pragma unroll
        for (int f = 0; f < 4; ++f)
            wf[f] = *(const bf16x8*)(Wb + woff[f]);
#pragma unroll
        for (int g = 0; g < 8; ++g)
            xf[g] = *(const bf16x8*)(Xb + xoff[g]);

        __builtin_amdgcn_s_setprio(1);
#pragma unroll
        for (int f = 0; f < 4; ++f)
#pragma unroll
            for (int g = 0; g < 8; ++g)
                acc[f][g] = __builtin_amdgcn_mfma_f32_16x16x32_bf16(
                    wf[f], xf[g], acc[f][g], 0, 0, 0);
        __builtin_amdgcn_s_setprio(0);
    }

    // ---- epilogue: D row = oc (quad*4+i), col = spatial (lane&15) ----
#pragma unroll
    for (int g = 0; g < 8; ++g) {
        const int mm = m0 + g * 16 + l16;
        const int bb = mm / PLANE;
        const int ss = mm - bb * PLANE;
        float* obase = out + (size_t)bb * (OC * PLANE) + ss;
#pragma unroll
        for (int f = 0; f < 4; ++f) {
            const int n = wv * 64 + f * 16 + quad * 4;
#pragma unroll
            for (int i = 0; i < 4; ++i)
                obase[(size_t)(n + i) * PLANE] = acc[f][g][i];
        }
    }
}

extern "C" void kernel_launch(void* const* d_in, const int* in_sizes, int n_in,
                              void* d_out, int out_size, void* d_ws, size_t ws_size,
                              hipStream_t stream) {
    const float* x    = (const float*)d_in[0];
    const float* W    = (const float*)d_in[1];
    const float* bias = (const float*)d_in[2];
    float* out = (float*)d_out;

    u16* xpad = (u16*)d_ws;
    u16* w3   = xpad + XPAD_ELEMS;

    zero_border<<<232, 256, 0, stream>>>((uint4*)xpad);
    pad_tr<<<dim3(HH, BATCH), 256, 0, stream>>>(x, xpad);
    pack_w<<<(W3_ELEMS + 255) / 256, 256, 0, stream>>>(W, w3);

    conv_main<<<784, 256, 0, stream>>>(xpad, w3, bias, out);
}

// Round 8
// 214.615 us; speedup vs baseline: 1.0637x; 1.0100x over previous
//
#include <hip/hip_runtime.h>
#include <hip/hip_bf16.h>
#include <stdint.h>

typedef unsigned short u16;
typedef unsigned int   u32;
typedef __bf16 bf16x8 __attribute__((ext_vector_type(8)));
typedef float  f32x4  __attribute__((ext_vector_type(4)));

#define BATCH 32
#define CIN   128
#define HH    56
#define WW    56
#define OC    256
#define HP    58
#define WP    58
#define PLANE  (HH*WW)    // 3136
#define KDIM   1152       // CIN*9
#define NT     36         // K tiles of 32 (KDIM/32)

#define XPAD_ELEMS (BATCH*HP*WP*CIN)   // NHWC padded bf16: 13,778,944
#define W3_ELEMS   (OC*KDIM)           // 294,912 bf16

#define GLDS16(g, l) __builtin_amdgcn_global_load_lds( \
    (const __attribute__((address_space(1))) void*)(g), \
    (__attribute__((address_space(3))) void*)(l), 16, 0, 0)

// ---- prep 0: zero top/bottom padded rows (h=0 and h=57 per image) ----
__global__ void zero_border(uint4* __restrict__ xp4) {
    int i = blockIdx.x * 256 + threadIdx.x;       // uint4 index
    if (i >= 64 * 928) return;                    // 64 rows x 928 uint4/row
    int row = i / 928;
    int off = i - row * 928;
    int b = row >> 1;
    int h = (row & 1) ? (HP - 1) : 0;
    xp4[((size_t)(b * HP + h) * WP * CIN) / 8 + off] = (uint4){0, 0, 0, 0};
}

// ---- prep 1: NCHW fp32 -> NHWC bf16, interior + left/right borders ----
__global__ __launch_bounds__(256) void pad_tr(const float* __restrict__ x,
                                              u16* __restrict__ xpad) {
    __shared__ u16 T16[56 * 130];   // [w][c], +2 pad -> bank stride 65 dwords
    const int h = blockIdx.x;
    const int b = blockIdx.y;
    const int tid = threadIdx.x;

    const float* src = x + (size_t)b * CIN * PLANE + h * WW;
#pragma unroll
    for (int j = 0; j < 14; ++j) {              // 14*256 = 3584 = 128*28
        int flat = j * 256 + tid;
        int c  = flat / 28;
        int wp = flat - c * 28;
        int w  = wp * 2;
        float2 v = *(const float2*)&src[(size_t)c * PLANE + w];
        __hip_bfloat16 b0 = __float2bfloat16(v.x);
        __hip_bfloat16 b1 = __float2bfloat16(v.y);
        T16[w * 130 + c]       = *(u16*)&b0;
        T16[(w + 1) * 130 + c] = *(u16*)&b1;
    }
    __syncthreads();

    const u32* T32 = (const u32*)T16;
    uint4* dst = (uint4*)(xpad + (size_t)(b * HP + h + 1) * WP * CIN);
#pragma unroll
    for (int j = 0; j < 4; ++j) {
        int g = j * 256 + tid;
        if (g < 928) {
            int wp = g >> 4, cq = g & 15;       // 16 uint4 = 128 ch per wp
            uint4 v = (uint4){0, 0, 0, 0};
            if (wp >= 1 && wp <= 56) {
                int w = wp - 1;
                v.x = T32[w * 65 + cq * 4 + 0];
                v.y = T32[w * 65 + cq * 4 + 1];
                v.z = T32[w * 65 + cq * 4 + 2];
                v.w = T32[w * 65 + cq * 4 + 3];
            }
            dst[g] = v;
        }
    }
}

// ---- prep 2: W[OC][C*9] fp32 -> bf16, layout [T=36][oc 256][k 32], with the
// 64B-row 4-chunk rotation PRE-APPLIED (proven-conflict-free): row = oc,
// rot = (row>>1)&3; LDS position p stores true chunk ((p - rot)&3).
// K-tile T covers r = T>>2 (kh*3+kw), channel quarter cq = T&3 (32 ch).
__global__ void pack_w(const float* __restrict__ W, u16* __restrict__ w3) {
    int o = blockIdx.x * blockDim.x + threadIdx.x;
    if (o >= W3_ELEMS) return;
    int T   = o >> 13;            // /8192 (256 oc x 32 k)
    int rem = o & 8191;
    int oc  = rem >> 5;
    int kk  = rem & 31;
    int p   = kk >> 3;            // chunk position 0..3
    int e   = kk & 7;
    int rot = (oc >> 1) & 3;
    int c32 = ((p - rot) & 3) * 8 + e;
    int r   = T >> 2;             // 0..8
    int c128 = (T & 3) * 32 + c32;
    float val = W[oc * KDIM + c128 * 9 + r];
    __hip_bfloat16 bv = __float2bfloat16(val);
    w3[o] = *(u16*)&bv;
}

// ---------------- main: implicit GEMM, 128x256 tile, BK=32 ------------------
// DEEP-RING pipeline (r8): every prior variant (r0,r2-r6: 83-98 us across
// schedule/tile/occupancy permutations) shared a depth-1 DMA pipeline whose
// vmcnt drains at a barrier each kt -> each kt serially pays the full
// global->LDS round trip (L2 latency + queuing of the 512-request 16B X
// gather), ~2000 cyc/kt vs ~350 of real work.  This version is the AITER
// pattern in the one untested regime (multi-block/CU + counted vmcnt):
// 3-deep LDS ring (72 KB -> still 2 blocks/CU), per kt:
//   { s_waitcnt vmcnt(12)   [tiles kt+1,kt+2 stay in flight — NEVER 0]
//     s_barrier             [all waves' tile-kt slices landed]
//     ds_reads + 32 MFMA    [no setprio: m190 — hurts lockstep GEMM]
//     s_barrier             [all reads of buf done -> WAR-safe]
//     issue(kt+3) into same buf }   ((kt+3)%3 == kt%3)
// Tail: vmcnt(6) at kt==NT-2, vmcnt(0) at NT-1.  DMA latency now amortizes
// over ~3 compute periods instead of gating every kt.
// LDS 64B rows, rotation rot=(r>>1)&3: ds_read_b128 conflict-free (measured
// 0 conflicts).  Grid 784 = 8*98 -> bijective XCD swizzle.
__global__ __launch_bounds__(256, 2) void conv_main(
    const u16* __restrict__ xpad,
    const u16* __restrict__ w3,
    const float* __restrict__ bias,
    float* __restrict__ out)
{
    __shared__ __align__(16) u16 WL[3][256 * 32];  // 16 KB / buf: [oc][k32]
    __shared__ __align__(16) u16 XL[3][128 * 32];  //  8 KB / buf: [sp][k32]

    const int tid  = threadIdx.x;
    const int lane = tid & 63;
    const int wv   = tid >> 6;      // wave = oc slice (64 oc each)
    const int l16  = lane & 15;
    const int quad = lane >> 4;

    // XCD-aware swizzle: 784 = 8 * 98 (divisible -> bijective)
    const int bid  = blockIdx.x;
    const int tile = (bid & 7) * 98 + (bid >> 3);
    const int m0   = tile * 128;

    // ---- X staging geometry: instr i covers rows i*64 + (tid>>2), pos tid&3
    const int srow = tid >> 2;      // 0..63
    const int spos = tid & 3;
    size_t xsrc[2];
#pragma unroll
    for (int i = 0; i < 2; ++i) {
        int r  = i * 64 + srow;                     // row 0..127
        int q  = (spos - ((r >> 1) & 3)) & 3;       // source chunk for rot
        int m  = m0 + r;
        int b  = m / PLANE;
        int s  = m - b * PLANE;
        int hh = s / WW;
        int ww = s - hh * WW;
        xsrc[i] = ((size_t)((b * HP + hh) * WP + ww) * CIN) * 2 + (size_t)q * 16;
    }
    const char* xb  = (const char*)xpad;
    const char* w3b = (const char*)w3;

    auto xkoff = [&](int kt) -> int {
        int r9 = kt >> 2;
        int kh = (r9 * 11) >> 5;                // r9/3 for r9 in 0..8
        int kw = r9 - kh * 3;
        return ((kh * WP + kw) * CIN + (kt & 3) * 32) * 2;
    };
    // one kt stage: W 16 KB (4 instr/thread, linear) + X 8 KB (2 instr/thread)
    auto issue = [&](int kt, int buf) {
        const char* wsrc = w3b + (size_t)kt * 16384 + tid * 16;
        char* wdst = (char*)WL[buf] + tid * 16;
#pragma unroll
        for (int j = 0; j < 4; ++j)
            GLDS16(wsrc + j * 4096, wdst + j * 4096);
        const int xko = xkoff(kt);
        char* xdst = (char*)XL[buf] + tid * 16;
#pragma unroll
        for (int i = 0; i < 2; ++i)
            GLDS16(xb + xsrc[i] + xko, xdst + i * 4096);
    };

    // frag ds_read byte offsets (64B rows, rot = (r>>1)&3)
    int woff[4], xoff[8];
#pragma unroll
    for (int f = 0; f < 4; ++f) {
        int r = wv * 64 + f * 16 + l16;
        woff[f] = r * 64 + (((quad + (r >> 1)) & 3) << 4);
    }
#pragma unroll
    for (int g = 0; g < 8; ++g) {
        int r = g * 16 + l16;
        xoff[g] = r * 64 + (((quad + (r >> 1)) & 3) << 4);
    }

    f32x4 acc[4][8];
#pragma unroll
    for (int f = 0; f < 4; ++f) {
        f32x4 bv = *(const f32x4*)&bias[wv * 64 + f * 16 + quad * 4];
#pragma unroll
        for (int g = 0; g < 8; ++g) acc[f][g] = bv;
    }

    // ---- prologue: fill the 3-deep ring (18 loads/wave in flight) ----
    issue(0, 0); issue(1, 1); issue(2, 2);

    int bufc = 0;
#pragma unroll 1
    for (int kt = 0; kt < NT; ++kt) {
        // counted drain: wait ONLY for tile kt's 6 loads; keep kt+1,kt+2
        // (12 loads) in flight across the barrier.
        if (kt < NT - 2)       asm volatile("s_waitcnt vmcnt(12)" ::: "memory");
        else if (kt == NT - 2) asm volatile("s_waitcnt vmcnt(6)"  ::: "memory");
        else                   asm volatile("s_waitcnt vmcnt(0)"  ::: "memory");
        asm volatile("s_barrier" ::: "memory");   // all slices of tile kt in

        const char* Wb = (const char*)WL[bufc];
        const char* Xb = (const char*)XL[bufc];
        bf16x8 wf[4], xf[8];
#pragma unroll
        for (int f = 0; f < 4; ++f)
            wf[f] = *(const bf16x8*)(Wb + woff[f]);
#pragma unroll
        for (int g = 0; g < 8; ++g)
            xf[g] = *(const bf16x8*)(Xb + xoff[g]);

#pragma unroll
        for (int f = 0; f < 4; ++f)
#pragma unroll
            for (int g = 0; g < 8; ++g)
                acc[f][g] = __builtin_amdgcn_mfma_f32_16x16x32_bf16(
                    wf[f], xf[g], acc[f][g], 0, 0, 0);

        asm volatile("s_barrier" ::: "memory");   // reads of bufc retired
        if (kt + 3 < NT) issue(kt + 3, bufc);     // refill same ring slot
        bufc = (bufc == 2) ? 0 : bufc + 1;
    }

    // ---- epilogue: D row = oc (quad*4+i), col = spatial (lane&15) ----
#pragma unroll
    for (int g = 0; g < 8; ++g) {
        const int mm = m0 + g * 16 + l16;
        const int bb = mm / PLANE;
        const int ss = mm - bb * PLANE;
        float* obase = out + (size_t)bb * (OC * PLANE) + ss;
#pragma unroll
        for (int f = 0; f < 4; ++f) {
            const int n = wv * 64 + f * 16 + quad * 4;
#pragma unroll
            for (int i = 0; i < 4; ++i)
                obase[(size_t)(n + i) * PLANE] = acc[f][g][i];
        }
    }
}

extern "C" void kernel_launch(void* const* d_in, const int* in_sizes, int n_in,
                              void* d_out, int out_size, void* d_ws, size_t ws_size,
                              hipStream_t stream) {
    const float* x    = (const float*)d_in[0];
    const float* W    = (const float*)d_in[1];
    const float* bias = (const float*)d_in[2];
    float* out = (float*)d_out;

    u16* xpad = (u16*)d_ws;
    u16* w3   = xpad + XPAD_ELEMS;

    zero_border<<<232, 256, 0, stream>>>((uint4*)xpad);
    pad_tr<<<dim3(HH, BATCH), 256, 0, stream>>>(x, xpad);
    pack_w<<<(W3_ELEMS + 255) / 256, 256, 0, stream>>>(W, w3);

    conv_main<<<784, 256, 0, stream>>>(xpad, w3, bias, out);
}